// Round 5
// baseline (1180.006 us; speedup 1.0000x reference)
//
#include <hip/hip_runtime.h>
#include <hip/hip_bf16.h>

// MultiHeadAttention: B=4, S=4096, D=512, H=2, PD=256, fp32 in/out.
// R5: q=64 per wave (2 q-blocks resident) -> every K/V LDS frag feeds 2 MFMAs,
// halving the ds_read_b128 count (the measured bottleneck pipe). 4 waves/block
// (kh x qg = 2x2), 128 q/block, BK=32/half double-buffered, ~450 VGPR,
// 1 wave/SIMD. LDS layout/swizzles identical to R4.

#define B_  4
#define S_  4096
#define D_  512
#define H_  2
#define PD_ 256
#define QSCALE 0.09016844f   // (1/sqrt(256)) * log2(e)

typedef __attribute__((ext_vector_type(4))) float f32x4;
typedef __attribute__((ext_vector_type(16))) float f32x16;
typedef __attribute__((ext_vector_type(8))) short short8;
typedef __attribute__((ext_vector_type(4))) short short4v;
typedef __attribute__((ext_vector_type(4))) unsigned u32x4;

static __device__ __forceinline__ short f2bf(float f) {
  unsigned u = __float_as_uint(f);
  u += 0x7fffu + ((u >> 16) & 1u);
  return (short)(u >> 16);
}
static __device__ __forceinline__ unsigned cvtpk(float a, float b) {
  unsigned r;
  asm("v_cvt_pk_bf16_f32 %0, %1, %2" : "=v"(r) : "v"(a), "v"(b));
  return r;
}
static __device__ __forceinline__ void gload16(const short* g, const short* l) {
  __builtin_amdgcn_global_load_lds((const __attribute__((address_space(1))) void*)g,
                                   (__attribute__((address_space(3))) void*)l,
                                   16, 0, 0);
}

// ---------------- kernel: convert x (f32) -> bf16 ----------------
__global__ void convert_x_kernel(const float* __restrict__ x, short* __restrict__ xb, int n8) {
  int i = blockIdx.x * blockDim.x + threadIdx.x;
  int stride = gridDim.x * blockDim.x;
  for (; i < n8; i += stride) {
    const f32x4* p = (const f32x4*)(x + (size_t)i * 8);
    f32x4 a = p[0], b = p[1];
    short8 v;
    v[0] = f2bf(a[0]); v[1] = f2bf(a[1]); v[2] = f2bf(a[2]); v[3] = f2bf(a[3]);
    v[4] = f2bf(b[0]); v[5] = f2bf(b[1]); v[6] = f2bf(b[2]); v[7] = f2bf(b[3]);
    *(short8*)(xb + (size_t)i * 8) = v;
  }
}

// ---------------- kernel: transpose W[k][n] f32 -> Wt[n][k] bf16 ----------------
__global__ __launch_bounds__(256) void transpose_w(
    const float* __restrict__ W0, const float* __restrict__ W1,
    const float* __restrict__ W2, const float* __restrict__ W3,
    short* __restrict__ T0, short* __restrict__ T1,
    short* __restrict__ T2, short* __restrict__ T3) {
  const float* W = (blockIdx.z == 0) ? W0 : (blockIdx.z == 1) ? W1 : (blockIdx.z == 2) ? W2 : W3;
  short* T = (blockIdx.z == 0) ? T0 : (blockIdx.z == 1) ? T1 : (blockIdx.z == 2) ? T2 : T3;
  __shared__ float tile[32][33];
  int tx = threadIdx.x & 31, ty = threadIdx.x >> 5;
  int r0 = blockIdx.x * 32, c0 = blockIdx.y * 32;
#pragma unroll
  for (int i = 0; i < 4; ++i)
    tile[ty + 8 * i][tx] = W[(size_t)(r0 + ty + 8 * i) * D_ + c0 + tx];
  __syncthreads();
#pragma unroll
  for (int i = 0; i < 4; ++i)
    T[(size_t)(c0 + ty + 8 * i) * D_ + r0 + tx] = f2bf(tile[tx][ty + 8 * i]);
}

// ---------------- kernel: transpose V (bf16) -> Vt[h][d][s] ----------------
// chunk-XOR pre-swizzle within each 32-key granule: slot = ((s>>3)&3) ^ ((d>>3)&3)
__global__ __launch_bounds__(256) void transpose_v(
    const short* __restrict__ Vw, short* __restrict__ Vt) {
  __shared__ short tile[64][68];
  int h = blockIdx.z;
  int s0 = blockIdx.x * 64, d0 = blockIdx.y * 64;
  const short* src = Vw + (size_t)h * S_ * PD_;
  short* dst = Vt + (size_t)h * S_ * PD_;
  int tx = threadIdx.x & 15, ty = threadIdx.x >> 4;
#pragma unroll
  for (int i = 0; i < 4; ++i) {
    short4v v = *(const short4v*)(src + (size_t)(s0 + ty + 16 * i) * PD_ + d0 + tx * 4);
    *(short4v*)&tile[ty + 16 * i][tx * 4] = v;
  }
  __syncthreads();
#pragma unroll
  for (int i = 0; i < 4; ++i) {
    int d = d0 + ty + 16 * i;
    short4v v;
#pragma unroll
    for (int j = 0; j < 4; ++j) v[j] = tile[tx * 4 + j][ty + 16 * i];
    int swz = ((tx >> 1) & 3) ^ ((d >> 3) & 3);   // chunk slot within 32-granule
    *(short4v*)(dst + (size_t)d * S_ + s0 + (tx >> 3) * 32 + swz * 8 + (tx & 1) * 4) = v;
  }
}

// ---------------- GEMM: C[M,N] = A[M,512](bf16) * Bt[N,512](bf16)^T + bias ----------------
// MODE 0: z=0 Q (scaled by QSCALE), z=1 K (chunk-XOR pre-swizzled), z=2 V.
// MODE 1: single weight, dense f32 out + bias.
template <int MODE>
__global__ __launch_bounds__(256, 2) void gemm_bt(
    const short* __restrict__ A,
    const short* __restrict__ Bt0, const short* __restrict__ Bt1, const short* __restrict__ Bt2,
    const float* __restrict__ b0, const float* __restrict__ b1, const float* __restrict__ b2,
    short* __restrict__ o0, short* __restrict__ o1, short* __restrict__ o2,
    float* __restrict__ fout) {
  __shared__ short sA[128 * 72];
  __shared__ short sB[128 * 72];

  const int tid = threadIdx.x;
  const int lane = tid & 63, wid = tid >> 6;
  const int wr = wid >> 1, wc = wid & 1;
  const int l15 = lane & 15, g = lane >> 4;
  const int m0 = blockIdx.x * 128, n0 = blockIdx.y * 128;

  const short* Bt = (MODE == 0) ? ((blockIdx.z == 0) ? Bt0 : (blockIdx.z == 1) ? Bt1 : Bt2) : Bt0;
  const float* bias = (MODE == 0) ? ((blockIdx.z == 0) ? b0 : (blockIdx.z == 1) ? b1 : b2) : b0;

  short8 pa[4], pb[4];

  auto loadT = [&](int kt) {
#pragma unroll
    for (int i = 0; i < 4; ++i) {
      int slot = tid + 256 * i;
      int r = slot >> 3, gg = slot & 7;
      pa[i] = *(const short8*)(A + (size_t)(m0 + r) * D_ + kt * 64 + 8 * gg);
      pb[i] = *(const short8*)(Bt + (size_t)(n0 + r) * D_ + kt * 64 + 8 * gg);
    }
  };
  auto storeT = [&]() {
#pragma unroll
    for (int i = 0; i < 4; ++i) {
      int slot = tid + 256 * i;
      int r = slot >> 3, gg = slot & 7;
      *(short8*)&sA[r * 72 + 8 * gg] = pa[i];
      *(short8*)&sB[r * 72 + 8 * gg] = pb[i];
    }
  };

  f32x4 acc[4][4];
#pragma unroll
  for (int i = 0; i < 4; ++i)
#pragma unroll
    for (int j = 0; j < 4; ++j) acc[i][j] = (f32x4)0.0f;

  loadT(0);
#pragma unroll 1
  for (int kt = 0; kt < 8; ++kt) {
    __syncthreads();
    storeT();
    if (kt < 7) loadT(kt + 1);
    __syncthreads();
#pragma unroll
    for (int s = 0; s < 2; ++s) {
      short8 a[4], b[4];
#pragma unroll
      for (int fr = 0; fr < 4; ++fr)
        a[fr] = *(const short8*)&sA[(wr * 64 + fr * 16 + l15) * 72 + 32 * s + 8 * g];
#pragma unroll
      for (int fc = 0; fc < 4; ++fc)
        b[fc] = *(const short8*)&sB[(wc * 64 + fc * 16 + l15) * 72 + 32 * s + 8 * g];
#pragma unroll
      for (int fr = 0; fr < 4; ++fr)
#pragma unroll
        for (int fc = 0; fc < 4; ++fc)
          acc[fr][fc] = __builtin_amdgcn_mfma_f32_16x16x32_bf16(a[fr], b[fc], acc[fr][fc], 0, 0, 0);
    }
  }

  if (MODE == 0) {
    short* dst = (blockIdx.z == 0) ? o0 : (blockIdx.z == 1) ? o1 : o2;
    const bool kswz = (blockIdx.z == 1);
    const float sc = (blockIdx.z == 0) ? QSCALE : 1.0f;
#pragma unroll
    for (int fc = 0; fc < 4; ++fc) {
      int n = n0 + wc * 64 + fc * 16 + l15;
      float bvv = bias[n];
      int h = n >> 8, pd = n & 255;
#pragma unroll
      for (int fr = 0; fr < 4; ++fr)
#pragma unroll
        for (int r = 0; r < 4; ++r) {
          int m = m0 + wr * 64 + fr * 16 + 4 * g + r;
          int bb = m >> 12, ss = m & 4095;
          int pdw = pd;
          if (kswz) {
            int ch = pd >> 3;
            pdw = (pd & 7) | (((ch & 24) | ((ch & 7) ^ (ss & 7))) << 3);
          }
          dst[((size_t)((bb * H_ + h) * S_ + ss)) * PD_ + pdw] = f2bf((acc[fr][fc][r] + bvv) * sc);
        }
    }
  } else {
#pragma unroll
    for (int fc = 0; fc < 4; ++fc) {
      int n = n0 + wc * 64 + fc * 16 + l15;
      float bvv = bias[n];
#pragma unroll
      for (int fr = 0; fr < 4; ++fr)
#pragma unroll
        for (int r = 0; r < 4; ++r) {
          int m = m0 + wr * 64 + fr * 16 + 4 * g + r;
          fout[(size_t)m * D_ + n] = acc[fr][fc][r] + bvv;
        }
    }
  }
}

// softmax for one q-block; S = f32x16 scores (log2 units), OARR = its o accum
#define SOFTMAX_QB(S, MRUN, LRUN, OARR, QBI)                                        \
  {                                                                                 \
    float a0 = fmaxf(S[0], S[1]),  a1 = fmaxf(S[2], S[3]);                          \
    float a2 = fmaxf(S[4], S[5]),  a3 = fmaxf(S[6], S[7]);                          \
    float a4 = fmaxf(S[8], S[9]),  a5 = fmaxf(S[10], S[11]);                        \
    float a6 = fmaxf(S[12], S[13]), a7 = fmaxf(S[14], S[15]);                       \
    a0 = fmaxf(a0, a1); a2 = fmaxf(a2, a3);                                         \
    a4 = fmaxf(a4, a5); a6 = fmaxf(a6, a7);                                         \
    a0 = fmaxf(a0, a2); a4 = fmaxf(a4, a6);                                         \
    float tmax = fmaxf(a0, a4);                                                     \
    tmax = fmaxf(tmax, __shfl_xor(tmax, 32));                                       \
    if (!__all(tmax <= MRUN + 8.0f)) {                                              \
      float mn = fmaxf(MRUN, tmax);                                                 \
      float resc = exp2f(MRUN - mn);                                                \
      MRUN = mn; LRUN *= resc;                                                      \
      if (!hi) sB1[w][QBI][l31] = resc;                                             \
      asm volatile("" ::: "memory");                                                \
      f32x4 rv0 = *(const f32x4*)&sB1[w][QBI][0 + hi * 4];                          \
      f32x4 rv1 = *(const f32x4*)&sB1[w][QBI][8 + hi * 4];                          \
      f32x4 rv2 = *(const f32x4*)&sB1[w][QBI][16 + hi * 4];                         \
      f32x4 rv3 = *(const f32x4*)&sB1[w][QBI][24 + hi * 4];                         \
      _Pragma("unroll")                                                             \
      for (int dcb = 0; dcb < 8; ++dcb)                                             \
        _Pragma("unroll")                                                           \
        for (int r = 0; r < 16; ++r) {                                              \
          float rr = (r < 4 ? rv0 : r < 8 ? rv1 : r < 12 ? rv2 : rv3)[r & 3];       \
          OARR[dcb][r] *= rr;                                                       \
        }                                                                           \
    }                                                                               \
    _Pragma("unroll")                                                               \
    for (int r = 0; r < 16; ++r) S[r] = exp2f(S[r] - MRUN);                         \
    float b0 = (S[0] + S[1]) + (S[2] + S[3]);                                       \
    float b1 = (S[4] + S[5]) + (S[6] + S[7]);                                       \
    b0 += (S[8] + S[9]) + (S[10] + S[11]);                                          \
    b1 += (S[12] + S[13]) + (S[14] + S[15]);                                        \
    float lsum = b0 + b1;                                                           \
    lsum += __shfl_xor(lsum, 32);                                                   \
    LRUN += lsum;                                                                   \
  }

#define REPACK(S, C, AF)                                                            \
  {                                                                                 \
    unsigned pk0 = cvtpk(S[8 * C + 0], S[8 * C + 1]);                               \
    unsigned pk1 = cvtpk(S[8 * C + 2], S[8 * C + 3]);                               \
    unsigned pk2 = cvtpk(S[8 * C + 4], S[8 * C + 5]);                               \
    unsigned pk3 = cvtpk(S[8 * C + 6], S[8 * C + 7]);                               \
    unsigned sh0 = __shfl_xor(pk0, 32);                                             \
    unsigned sh1 = __shfl_xor(pk1, 32);                                             \
    unsigned sh2 = __shfl_xor(pk2, 32);                                             \
    unsigned sh3 = __shfl_xor(pk3, 32);                                             \
    u32x4 ua;                                                                       \
    ua[0] = hi ? sh2 : pk0;                                                         \
    ua[1] = hi ? sh3 : pk1;                                                         \
    ua[2] = hi ? pk2 : sh0;                                                         \
    ua[3] = hi ? pk3 : sh1;                                                         \
    AF = *(short8*)&ua;                                                             \
  }

// ---------------- flash attention, 4 waves, q=64/wave (2:1 frag reuse) ----------------
// Block: 256 thr = 4 waves; wave w: kh = w>>1 (key half), qg = w&1 (64-q group).
// Each wave holds TWO 32-q blocks in registers; every K/V frag read once, used twice.
// BK=32/half double-buffered (128KB LDS). Merge kh pairs at end (w <-> w^2).
__global__ __launch_bounds__(256, 1) void attn5_kernel(
    const short* __restrict__ Qw, const short* __restrict__ Kw,
    const short* __restrict__ Vt, short* __restrict__ ATT) {
  __shared__ __align__(16) char smem[133120];  // staging 128KB; merge 2x66560B
  __shared__ float sMm[4][2][32];
  __shared__ float sB1[4][2][32];
  __shared__ float sMl[2][2][32];

  const int tid = threadIdx.x, lane = tid & 63, w = tid >> 6;
  const int l31 = lane & 31, hi = lane >> 5;
  const int head = blockIdx.x & 7, qt = blockIdx.x >> 3;
  const int kh = w >> 1, qg = w & 1;
  const size_t hoff = (size_t)head * S_ * PD_;
  const short* Qh = Qw + hoff;
  const short* Kh = Kw + hoff;
  const short* Vh = Vt + hoff;                 // [PD][S], pre-swizzled 32-granule

  // Q fragments for both q-blocks (B-operand of swapped QK); QSCALE pre-folded.
  short8 qf0[16], qf1[16];
  {
    const short* qp = Qh + (size_t)(qt * 128 + qg * 64 + l31) * PD_;
#pragma unroll
    for (int dc = 0; dc < 16; ++dc) {
      qf0[dc] = *(const short8*)(qp + dc * 16 + hi * 8);
      qf1[dc] = *(const short8*)(qp + 32 * PD_ + dc * 16 + hi * 8);
    }
  }

  // precomputed swizzled LDS read addresses (same layout as R4)
  const int mm = l31 & 7, pp = (l31 >> 1) & 3, q3 = l31 >> 3;
  int kaddr[4];
#pragma unroll
  for (int b = 0; b < 4; ++b)
    kaddr[b] = kh * 32768 + l31 * 512 + ((b ^ pp) << 5) + ((hi ^ (mm & 1)) << 4);
  int vaddr[2];
#pragma unroll
  for (int c = 0; c < 2; ++c)
    vaddr[c] = 65536 + kh * 32768 + l31 * 64 + (((2 * c + hi) ^ q3) << 4);

  f32x16 o0[8], o1[8];
#pragma unroll
  for (int i = 0; i < 8; ++i) { o0[i] = (f32x16)0.0f; o1[i] = (f32x16)0.0f; }
  float mrun0 = -3.0e38f, lrun0 = 0.0f;
  float mrun1 = -3.0e38f, lrun1 = 0.0f;

  auto stage = [&](int buf, int t) {
    const short* kt = Kh + (size_t)(t * 32) * PD_;
#pragma unroll
    for (int i = 0; i < 8; ++i) {
      int s = tid + 256 * i;                  // 0..2047
      int half = s >> 10, s1 = s & 1023;      // s1: key=s1>>5, chunk=s1&31
      gload16(kt + (size_t)(half * 2048) * PD_ + (s1 >> 5) * PD_ + (s1 & 31) * 8,
              (const short*)(smem + half * 32768 + buf * 16384 + s1 * 16));
    }
    const short* vt = Vh + t * 32;
#pragma unroll
    for (int i = 0; i < 8; ++i) {
      int s = tid + 256 * i;
      int half = s >> 10, s1 = s & 1023;      // s1: d=s1>>2, chunk=s1&3
      gload16(vt + (size_t)(s1 >> 2) * S_ + half * 2048 + (s1 & 3) * 8,
              (const short*)(smem + 65536 + half * 32768 + buf * 16384 + s1 * 16));
    }
  };

  auto compute = [&](int buf) {
    // ---- QK^T (swapped): one K-frag read feeds both q-blocks
    f32x16 s0 = (f32x16)0.0f, s1 = (f32x16)0.0f;
#pragma unroll
    for (int a = 0; a < 4; ++a)
#pragma unroll
      for (int b = 0; b < 4; ++b) {
        short8 kf = *(const short8*)(smem + kaddr[b] + a * 128 + buf * 16384);
        s0 = __builtin_amdgcn_mfma_f32_32x32x16_bf16(kf, qf0[4 * a + b], s0, 0, 0, 0);
        s1 = __builtin_amdgcn_mfma_f32_32x32x16_bf16(kf, qf1[4 * a + b], s1, 0, 0, 0);
      }

    SOFTMAX_QB(s0, mrun0, lrun0, o0, 0)
    SOFTMAX_QB(s1, mrun1, lrun1, o1, 1)

    // ---- PV: one V-frag read feeds both q-blocks
#pragma unroll
    for (int c = 0; c < 2; ++c) {
      short8 af0, af1;
      REPACK(s0, c, af0)
      REPACK(s1, c, af1)
#pragma unroll
      for (int dcb = 0; dcb < 8; ++dcb) {
        short8 vf = *(const short8*)(smem + vaddr[c] + dcb * 2048 + buf * 16384);
        o0[dcb] = __builtin_amdgcn_mfma_f32_32x32x16_bf16(af0, vf, o0[dcb], 0, 0, 0);
        o1[dcb] = __builtin_amdgcn_mfma_f32_32x32x16_bf16(af1, vf, o1[dcb], 0, 0, 0);
      }
    }
  };

  stage(0, 0);
#pragma unroll 1
  for (int t = 0; t < 64; t += 2) {
    __syncthreads();               // buf0 staged; all waves done reading buf1
    stage(1, t + 1);
    compute(0);
    __syncthreads();               // buf1 staged; all waves done reading buf0
    if (t + 2 < 64) stage(0, t + 2);
    compute(1);
  }

  // ---- merge key-half pairs (w <-> w^2 share q-rows) ----
  __syncthreads();
  if (!hi) { sMm[w][0][l31] = mrun0; sMm[w][1][l31] = mrun1; }
  __syncthreads();
  {
    float mo0 = sMm[w ^ 2][0][l31], mo1 = sMm[w ^ 2][1][l31];
    float mf0 = fmaxf(mrun0, mo0), mf1 = fmaxf(mrun1, mo1);
    float sc0 = exp2f(mrun0 - mf0), sc1 = exp2f(mrun1 - mf1);
    lrun0 *= sc0; lrun1 *= sc1;
    if (!hi) { sB1[w][0][l31] = sc0; sB1[w][1][l31] = sc1; }
    asm volatile("" ::: "memory");
#pragma unroll
    for (int qb = 0; qb < 2; ++qb) {
      f32x4 rv0 = *(const f32x4*)&sB1[w][qb][0 + hi * 4];
      f32x4 rv1 = *(const f32x4*)&sB1[w][qb][8 + hi * 4];
      f32x4 rv2 = *(const f32x4*)&sB1[w][qb][16 + hi * 4];
      f32x4 rv3 = *(const f32x4*)&sB1[w][qb][24 + hi * 4];
#pragma unroll
      for (int dcb = 0; dcb < 8; ++dcb)
#pragma unroll
        for (int r = 0; r < 16; ++r) {
          float rr = (r < 4 ? rv0 : r < 8 ? rv1 : r < 12 ? rv2 : rv3)[r & 3];
          if (qb == 0) o0[dcb][r] *= rr; else o1[dcb][r] *= rr;
        }
    }
    if (w >= 2 && !hi) { sMl[w - 2][0][l31] = lrun0; sMl[w - 2][1][l31] = lrun1; }
  }
  __syncthreads();
  float* mb = (float*)smem;
  if (w >= 2) {                              // kh=1 deposits scaled o (both q-blocks)
    float* rg = mb + (size_t)qg * 16640;
#pragma unroll
    for (int dcb = 0; dcb < 8; ++dcb)
#pragma unroll
      for (int r4 = 0; r4 < 4; ++r4) {
        f32x4 v0, v1;
#pragma unroll
        for (int j = 0; j < 4; ++j) { v0[j] = o0[dcb][4 * r4 + j]; v1[j] = o1[dcb][4 * r4 + j]; }
        *(f32x4*)&rg[(size_t)(dcb * 4 + r4) * 260 + lane * 4] = v0;
        *(f32x4*)&rg[(size_t)(32 + dcb * 4 + r4) * 260 + lane * 4] = v1;
      }
  }
  __syncthreads();
  if (w < 2) {                               // kh=0 combines + epilogue (64 q-rows)
    float* rg = mb + (size_t)qg * 16640;
#pragma unroll
    for (int dcb = 0; dcb < 8; ++dcb)
#pragma unroll
      for (int r4 = 0; r4 < 4; ++r4) {
        f32x4 v0 = *(const f32x4*)&rg[(size_t)(dcb * 4 + r4) * 260 + lane * 4];
        f32x4 v1 = *(const f32x4*)&rg[(size_t)(32 + dcb * 4 + r4) * 260 + lane * 4];
#pragma unroll
        for (int j = 0; j < 4; ++j) { o0[dcb][4 * r4 + j] += v0[j]; o1[dcb][4 * r4 + j] += v1[j]; }
      }
    lrun0 += sMl[qg][0][l31];
    lrun1 += sMl[qg][1][l31];
    if (!hi) { sB1[w][0][l31] = 1.0f / lrun0; sB1[w][1][l31] = 1.0f / lrun1; }
    asm volatile("" ::: "memory");
    const int bb = head >> 1, hh = head & 1;
#pragma unroll
    for (int qb = 0; qb < 2; ++qb) {
      f32x4 iv0 = *(const f32x4*)&sB1[w][qb][0 + hi * 4];
      f32x4 iv1 = *(const f32x4*)&sB1[w][qb][8 + hi * 4];
      f32x4 iv2 = *(const f32x4*)&sB1[w][qb][16 + hi * 4];
      f32x4 iv3 = *(const f32x4*)&sB1[w][qb][24 + hi * 4];
#pragma unroll
      for (int r = 0; r < 16; ++r) {
        int q = qt * 128 + qg * 64 + qb * 32 + (r & 3) + 8 * (r >> 2) + 4 * hi;
        float iv = (r < 4 ? iv0 : r < 8 ? iv1 : r < 12 ? iv2 : iv3)[r & 3];
        size_t base = ((size_t)(bb * S_ + q)) * D_ + hh * PD_;
#pragma unroll
        for (int dcb = 0; dcb < 8; ++dcb)
          ATT[base + dcb * 32 + l31] = f2bf((qb == 0 ? o0[dcb][r] : o1[dcb][r]) * iv);
      }
    }
  }
}

// ---------------- launcher ----------------
extern "C" void kernel_launch(void* const* d_in, const int* in_sizes, int n_in,
                              void* d_out, int out_size, void* d_ws, size_t ws_size,
                              hipStream_t stream) {
  const float* x  = (const float*)d_in[0];
  const float* Wq = (const float*)d_in[1];
  const float* bq = (const float*)d_in[2];
  const float* Wk = (const float*)d_in[3];
  const float* bk = (const float*)d_in[4];
  const float* Wv = (const float*)d_in[5];
  const float* bv = (const float*)d_in[6];
  const float* Wo = (const float*)d_in[7];
  const float* bo = (const float*)d_in[8];
  float* out = (float*)d_out;

  char* ws = (char*)d_ws;
  const size_t WSZ = (size_t)D_ * D_ * 2;             // 512KB per transposed weight
  const size_t QSZ = (size_t)B_ * H_ * S_ * PD_ * 2;  // 16.78MB
  short* wtq = (short*)(ws);
  short* wtk = (short*)(ws + WSZ);
  short* wtv = (short*)(ws + 2 * WSZ);
  short* wto = (short*)(ws + 3 * WSZ);
  short* Qw  = (short*)(ws + 4 * WSZ);
  short* Kw  = (short*)(ws + 4 * WSZ + QSZ);
  short* Vw  = (short*)(ws + 4 * WSZ + 2 * QSZ);
  short* ATT = (short*)(ws + 4 * WSZ + 3 * QSZ);  // also used as xb (dead before attn writes)
  short* XB  = ATT;
  short* Vtp = (short*)d_out;  // V^T scratch lives in d_out; overwritten by final GEMM

  convert_x_kernel<<<dim3(2048), dim3(256), 0, stream>>>(x, XB, (B_ * S_ * D_) / 8);
  transpose_w<<<dim3(16, 16, 4), dim3(256), 0, stream>>>(Wq, Wk, Wv, Wo, wtq, wtk, wtv, wto);
  gemm_bt<0><<<dim3(128, 4, 3), dim3(256), 0, stream>>>(
      XB, wtq, wtk, wtv, bq, bk, bv, Qw, Kw, Vw, (float*)nullptr);
  transpose_v<<<dim3(64, 4, 8), dim3(256), 0, stream>>>(Vw, Vtp);
  attn5_kernel<<<dim3(256), dim3(256), 0, stream>>>(Qw, Kw, Vtp, ATT);
  gemm_bt<1><<<dim3(128, 4, 1), dim3(256), 0, stream>>>(
      ATT, wto, wto, wto, bo, bo, bo, nullptr, nullptr, nullptr, out);
}

// Round 7
// 488.485 us; speedup vs baseline: 2.4156x; 2.4156x over previous
//
#include <hip/hip_runtime.h>
#include <hip/hip_bf16.h>

// MultiHeadAttention: B=4, S=4096, D=512, H=2, PD=256, fp32 in/out.
// R7 = R6 with the vaddr double-base bug fixed (V reads were OOB in LDS).
// Deferred-SM pipeline: region t does QK(t) [MFMA] || SM(t-1) [VALU] ->
// PV(t-1) [MFMA]. K double-buffered, V triple-buffered. 160KB LDS exactly.

#define B_  4
#define S_  4096
#define D_  512
#define H_  2
#define PD_ 256
#define QSCALE 0.09016844f   // (1/sqrt(256)) * log2(e)

typedef __attribute__((ext_vector_type(4))) float f32x4;
typedef __attribute__((ext_vector_type(16))) float f32x16;
typedef __attribute__((ext_vector_type(8))) short short8;
typedef __attribute__((ext_vector_type(4))) short short4v;
typedef __attribute__((ext_vector_type(4))) unsigned u32x4;

static __device__ __forceinline__ short f2bf(float f) {
  unsigned u = __float_as_uint(f);
  u += 0x7fffu + ((u >> 16) & 1u);
  return (short)(u >> 16);
}
static __device__ __forceinline__ unsigned cvtpk(float a, float b) {
  unsigned r;
  asm("v_cvt_pk_bf16_f32 %0, %1, %2" : "=v"(r) : "v"(a), "v"(b));
  return r;
}
static __device__ __forceinline__ void gload16(const short* g, const short* l) {
  __builtin_amdgcn_global_load_lds((const __attribute__((address_space(1))) void*)g,
                                   (__attribute__((address_space(3))) void*)l,
                                   16, 0, 0);
}

// ---------------- kernel: convert x (f32) -> bf16 ----------------
__global__ void convert_x_kernel(const float* __restrict__ x, short* __restrict__ xb, int n8) {
  int i = blockIdx.x * blockDim.x + threadIdx.x;
  int stride = gridDim.x * blockDim.x;
  for (; i < n8; i += stride) {
    const f32x4* p = (const f32x4*)(x + (size_t)i * 8);
    f32x4 a = p[0], b = p[1];
    short8 v;
    v[0] = f2bf(a[0]); v[1] = f2bf(a[1]); v[2] = f2bf(a[2]); v[3] = f2bf(a[3]);
    v[4] = f2bf(b[0]); v[5] = f2bf(b[1]); v[6] = f2bf(b[2]); v[7] = f2bf(b[3]);
    *(short8*)(xb + (size_t)i * 8) = v;
  }
}

// ---------------- kernel: transpose W[k][n] f32 -> Wt[n][k] bf16 ----------------
__global__ __launch_bounds__(256) void transpose_w(
    const float* __restrict__ W0, const float* __restrict__ W1,
    const float* __restrict__ W2, const float* __restrict__ W3,
    short* __restrict__ T0, short* __restrict__ T1,
    short* __restrict__ T2, short* __restrict__ T3) {
  const float* W = (blockIdx.z == 0) ? W0 : (blockIdx.z == 1) ? W1 : (blockIdx.z == 2) ? W2 : W3;
  short* T = (blockIdx.z == 0) ? T0 : (blockIdx.z == 1) ? T1 : (blockIdx.z == 2) ? T2 : T3;
  __shared__ float tile[32][33];
  int tx = threadIdx.x & 31, ty = threadIdx.x >> 5;
  int r0 = blockIdx.x * 32, c0 = blockIdx.y * 32;
#pragma unroll
  for (int i = 0; i < 4; ++i)
    tile[ty + 8 * i][tx] = W[(size_t)(r0 + ty + 8 * i) * D_ + c0 + tx];
  __syncthreads();
#pragma unroll
  for (int i = 0; i < 4; ++i)
    T[(size_t)(c0 + ty + 8 * i) * D_ + r0 + tx] = f2bf(tile[tx][ty + 8 * i]);
}

// ---------------- kernel: transpose V (bf16) -> Vt[h][d][s] ----------------
// chunk-XOR pre-swizzle within each 32-key granule: slot = ((s>>3)&3) ^ ((d>>3)&3)
__global__ __launch_bounds__(256) void transpose_v(
    const short* __restrict__ Vw, short* __restrict__ Vt) {
  __shared__ short tile[64][68];
  int h = blockIdx.z;
  int s0 = blockIdx.x * 64, d0 = blockIdx.y * 64;
  const short* src = Vw + (size_t)h * S_ * PD_;
  short* dst = Vt + (size_t)h * S_ * PD_;
  int tx = threadIdx.x & 15, ty = threadIdx.x >> 4;
#pragma unroll
  for (int i = 0; i < 4; ++i) {
    short4v v = *(const short4v*)(src + (size_t)(s0 + ty + 16 * i) * PD_ + d0 + tx * 4);
    *(short4v*)&tile[ty + 16 * i][tx * 4] = v;
  }
  __syncthreads();
#pragma unroll
  for (int i = 0; i < 4; ++i) {
    int d = d0 + ty + 16 * i;
    short4v v;
#pragma unroll
    for (int j = 0; j < 4; ++j) v[j] = tile[tx * 4 + j][ty + 16 * i];
    int swz = ((tx >> 1) & 3) ^ ((d >> 3) & 3);   // chunk slot within 32-granule
    *(short4v*)(dst + (size_t)d * S_ + s0 + (tx >> 3) * 32 + swz * 8 + (tx & 1) * 4) = v;
  }
}

// ---------------- GEMM: C[M,N] = A[M,512](bf16) * Bt[N,512](bf16)^T + bias ----------------
// MODE 0: z=0 Q (scaled by QSCALE), z=1 K (chunk-XOR pre-swizzled), z=2 V.
// MODE 1: single weight, dense f32 out + bias.
template <int MODE>
__global__ __launch_bounds__(256, 2) void gemm_bt(
    const short* __restrict__ A,
    const short* __restrict__ Bt0, const short* __restrict__ Bt1, const short* __restrict__ Bt2,
    const float* __restrict__ b0, const float* __restrict__ b1, const float* __restrict__ b2,
    short* __restrict__ o0, short* __restrict__ o1, short* __restrict__ o2,
    float* __restrict__ fout) {
  __shared__ short sA[128 * 72];
  __shared__ short sB[128 * 72];

  const int tid = threadIdx.x;
  const int lane = tid & 63, wid = tid >> 6;
  const int wr = wid >> 1, wc = wid & 1;
  const int l15 = lane & 15, g = lane >> 4;
  const int m0 = blockIdx.x * 128, n0 = blockIdx.y * 128;

  const short* Bt = (MODE == 0) ? ((blockIdx.z == 0) ? Bt0 : (blockIdx.z == 1) ? Bt1 : Bt2) : Bt0;
  const float* bias = (MODE == 0) ? ((blockIdx.z == 0) ? b0 : (blockIdx.z == 1) ? b1 : b2) : b0;

  short8 pa[4], pb[4];

  auto loadT = [&](int kt) {
#pragma unroll
    for (int i = 0; i < 4; ++i) {
      int slot = tid + 256 * i;
      int r = slot >> 3, gg = slot & 7;
      pa[i] = *(const short8*)(A + (size_t)(m0 + r) * D_ + kt * 64 + 8 * gg);
      pb[i] = *(const short8*)(Bt + (size_t)(n0 + r) * D_ + kt * 64 + 8 * gg);
    }
  };
  auto storeT = [&]() {
#pragma unroll
    for (int i = 0; i < 4; ++i) {
      int slot = tid + 256 * i;
      int r = slot >> 3, gg = slot & 7;
      *(short8*)&sA[r * 72 + 8 * gg] = pa[i];
      *(short8*)&sB[r * 72 + 8 * gg] = pb[i];
    }
  };

  f32x4 acc[4][4];
#pragma unroll
  for (int i = 0; i < 4; ++i)
#pragma unroll
    for (int j = 0; j < 4; ++j) acc[i][j] = (f32x4)0.0f;

  loadT(0);
#pragma unroll 1
  for (int kt = 0; kt < 8; ++kt) {
    __syncthreads();
    storeT();
    if (kt < 7) loadT(kt + 1);
    __syncthreads();
#pragma unroll
    for (int s = 0; s < 2; ++s) {
      short8 a[4], b[4];
#pragma unroll
      for (int fr = 0; fr < 4; ++fr)
        a[fr] = *(const short8*)&sA[(wr * 64 + fr * 16 + l15) * 72 + 32 * s + 8 * g];
#pragma unroll
      for (int fc = 0; fc < 4; ++fc)
        b[fc] = *(const short8*)&sB[(wc * 64 + fc * 16 + l15) * 72 + 32 * s + 8 * g];
#pragma unroll
      for (int fr = 0; fr < 4; ++fr)
#pragma unroll
        for (int fc = 0; fc < 4; ++fc)
          acc[fr][fc] = __builtin_amdgcn_mfma_f32_16x16x32_bf16(a[fr], b[fc], acc[fr][fc], 0, 0, 0);
    }
  }

  if (MODE == 0) {
    short* dst = (blockIdx.z == 0) ? o0 : (blockIdx.z == 1) ? o1 : o2;
    const bool kswz = (blockIdx.z == 1);
    const float sc = (blockIdx.z == 0) ? QSCALE : 1.0f;
#pragma unroll
    for (int fc = 0; fc < 4; ++fc) {
      int n = n0 + wc * 64 + fc * 16 + l15;
      float bvv = bias[n];
      int h = n >> 8, pd = n & 255;
#pragma unroll
      for (int fr = 0; fr < 4; ++fr)
#pragma unroll
        for (int r = 0; r < 4; ++r) {
          int m = m0 + wr * 64 + fr * 16 + 4 * g + r;
          int bb = m >> 12, ss = m & 4095;
          int pdw = pd;
          if (kswz) {
            int ch = pd >> 3;
            pdw = (pd & 7) | (((ch & 24) | ((ch & 7) ^ (ss & 7))) << 3);
          }
          dst[((size_t)((bb * H_ + h) * S_ + ss)) * PD_ + pdw] = f2bf((acc[fr][fc][r] + bvv) * sc);
        }
    }
  } else {
#pragma unroll
    for (int fc = 0; fc < 4; ++fc) {
      int n = n0 + wc * 64 + fc * 16 + l15;
      float bvv = bias[n];
#pragma unroll
      for (int fr = 0; fr < 4; ++fr)
#pragma unroll
        for (int r = 0; r < 4; ++r) {
          int m = m0 + wr * 64 + fr * 16 + 4 * g + r;
          fout[(size_t)m * D_ + n] = acc[fr][fc][r] + bvv;
        }
    }
  }
}

// ---------------- flash attention R7: deferred-SM pipeline ----------------
// 8 waves (512 thr): kh = w>>2 (key half), qg = w&3 (32-q group). 128 q/block.
// LDS 160KB exactly: K [2 buf][2 half][32 key][32 chunk*16B] at 0 (64KB),
//                    V [3 buf][2 half][256 d][4 chunk*16B] at 65536 (96KB).
// Region t: barrier; stage K(t+1)->kb[(t+1)&1], V(t+1)->vb[(t+1)%3];
//           QK(t) from kb[t&1]; SM(t-1); PV(t-1) from vb[(t-1)%3].
__global__ __launch_bounds__(512, 2) void attn6_kernel(
    const short* __restrict__ Qw, const short* __restrict__ Kw,
    const short* __restrict__ Vt, short* __restrict__ ATT) {
  __shared__ __align__(16) char smem[163840];

  const int tid = threadIdx.x, lane = tid & 63, w = tid >> 6;
  const int l31 = lane & 31, hi = lane >> 5;
  const int head = blockIdx.x & 7, qb = blockIdx.x >> 3;
  const int kh = w >> 2, qg = w & 3;
  const size_t hoff = (size_t)head * S_ * PD_;
  const short* Qh = Qw + hoff;
  const short* Vh = Vt + hoff;                 // [PD][S], pre-swizzled 32-granule

  // Q fragments (B-operand of swapped QK); QSCALE pre-folded.
  const int qrow = qb * 128 + qg * 32 + l31;
  short8 qf[16];
#pragma unroll
  for (int dc = 0; dc < 16; ++dc)
    qf[dc] = *(const short8*)(Qh + (size_t)qrow * PD_ + dc * 16 + hi * 8);

  // LDS read addresses (within-half layout identical to R4; half stride 16384)
  const int mm = l31 & 7, pp = (l31 >> 1) & 3, q3 = l31 >> 3;
  int kaddr[4];
#pragma unroll
  for (int b = 0; b < 4; ++b)
    kaddr[b] = kh * 16384 + l31 * 512 + ((b ^ pp) << 5) + ((hi ^ (mm & 1)) << 4);
  int vaddr[2];
#pragma unroll
  for (int c = 0; c < 2; ++c)
    vaddr[c] = kh * 16384 + l31 * 64 + (((2 * c + hi) ^ q3) << 4);   // FIX: no 65536 here

  // staging bases: 3 VGPRs + literal offsets (uniform ptrs kg/vg live in SGPR)
  const int lk0 = tid * 16;                        // LDS byte base (K and V)
  const int gk0 = (tid >> 5) * PD_ + (tid & 31) * 8;  // K global short-offset
  const int gv0 = (tid >> 2) * S_ + (tid & 3) * 8;    // V global short-offset
  const short* kg = Kw + hoff;                     // -> K(t+1)*32*PD when staging
  const short* vg = Vh;                            // -> + t*32 along s

  f32x16 o[8];
#pragma unroll
  for (int i = 0; i < 8; ++i) o[i] = (f32x16)0.0f;
  f32x16 sA, sB;
  float mrun = -3.0e38f, lrun = 0.0f;

#define STAGE_K(KN)                                                                  \
  gload16(kg + gk0,          (const short*)(smem + (KN) * 32768 + lk0));             \
  gload16(kg + gk0 + 4096,   (const short*)(smem + (KN) * 32768 + 8192 + lk0));      \
  gload16(kg + gk0 + 524288, (const short*)(smem + (KN) * 32768 + 16384 + lk0));     \
  gload16(kg + gk0 + 528384, (const short*)(smem + (KN) * 32768 + 24576 + lk0));

#define STAGE_V(VS)                                                                  \
  gload16(vg + gv0,          (const short*)(smem + 65536 + (VS) * 32768 + lk0));     \
  gload16(vg + gv0 + 524288, (const short*)(smem + 65536 + (VS) * 32768 + 8192 + lk0)); \
  gload16(vg + gv0 + 2048,   (const short*)(smem + 65536 + (VS) * 32768 + 16384 + lk0)); \
  gload16(vg + gv0 + 526336, (const short*)(smem + 65536 + (VS) * 32768 + 24576 + lk0));

#define QK_(SCUR, KC)                                                                \
  {                                                                                  \
    f32x16 _a = (f32x16)0.0f, _b = (f32x16)0.0f;                                     \
    __builtin_amdgcn_s_setprio(1);                                                   \
    _Pragma("unroll")                                                                \
    for (int a = 0; a < 4; ++a) {                                                    \
      _Pragma("unroll")                                                              \
      for (int b = 0; b < 4; ++b) {                                                  \
        short8 kf = *(const short8*)(smem + (KC) * 32768 + kaddr[b] + a * 128);      \
        if (b & 1) _b = __builtin_amdgcn_mfma_f32_32x32x16_bf16(kf, qf[4 * a + b], _b, 0, 0, 0); \
        else       _a = __builtin_amdgcn_mfma_f32_32x32x16_bf16(kf, qf[4 * a + b], _a, 0, 0, 0); \
      }                                                                              \
    }                                                                                \
    __builtin_amdgcn_s_setprio(0);                                                   \
    SCUR = _a + _b;                                                                  \
  }

#define SM_(S)                                                                       \
  {                                                                                  \
    float t0 = fmaxf(S[0], S[1]),   t1 = fmaxf(S[2], S[3]);                          \
    float t2 = fmaxf(S[4], S[5]),   t3 = fmaxf(S[6], S[7]);                          \
    float t4 = fmaxf(S[8], S[9]),   t5 = fmaxf(S[10], S[11]);                        \
    float t6 = fmaxf(S[12], S[13]), t7 = fmaxf(S[14], S[15]);                        \
    t0 = fmaxf(t0, t1); t2 = fmaxf(t2, t3); t4 = fmaxf(t4, t5); t6 = fmaxf(t6, t7);  \
    t0 = fmaxf(t0, t2); t4 = fmaxf(t4, t6);                                          \
    float tmax = fmaxf(t0, t4);                                                      \
    tmax = fmaxf(tmax, __shfl_xor(tmax, 32));                                        \
    if (!__all(tmax <= mrun + 8.0f)) {                                               \
      float mn = fmaxf(mrun, tmax);                                                  \
      float resc = exp2f(mrun - mn);                                                 \
      mrun = mn; lrun *= resc;                                                       \
      _Pragma("unroll")                                                              \
      for (int r = 0; r < 16; ++r) {                                                 \
        float rr = __shfl(resc, (r & 3) + 8 * (r >> 2) + 4 * hi, 64);                \
        _Pragma("unroll")                                                            \
        for (int d = 0; d < 8; ++d) o[d][r] *= rr;                                   \
      }                                                                              \
    }                                                                                \
    _Pragma("unroll")                                                                \
    for (int r = 0; r < 16; ++r) S[r] = exp2f(S[r] - mrun);                          \
    float u0 = (S[0] + S[1]) + (S[2] + S[3]);                                        \
    float u1 = (S[4] + S[5]) + (S[6] + S[7]);                                        \
    u0 += (S[8] + S[9]) + (S[10] + S[11]);                                           \
    u1 += (S[12] + S[13]) + (S[14] + S[15]);                                         \
    float ls = u0 + u1;                                                              \
    ls += __shfl_xor(ls, 32);                                                        \
    lrun += ls;                                                                      \
  }

#define PV_(S, VP)                                                                   \
  {                                                                                  \
    _Pragma("unroll")                                                                \
    for (int c = 0; c < 2; ++c) {                                                    \
      unsigned pk0 = cvtpk(S[8 * c + 0], S[8 * c + 1]);                              \
      unsigned pk1 = cvtpk(S[8 * c + 2], S[8 * c + 3]);                              \
      unsigned pk2 = cvtpk(S[8 * c + 4], S[8 * c + 5]);                              \
      unsigned pk3 = cvtpk(S[8 * c + 6], S[8 * c + 7]);                              \
      unsigned sh0 = __shfl_xor(pk0, 32);                                            \
      unsigned sh1 = __shfl_xor(pk1, 32);                                            \
      unsigned sh2 = __shfl_xor(pk2, 32);                                            \
      unsigned sh3 = __shfl_xor(pk3, 32);                                            \
      u32x4 ua;                                                                      \
      ua[0] = hi ? sh2 : pk0;                                                        \
      ua[1] = hi ? sh3 : pk1;                                                        \
      ua[2] = hi ? pk2 : sh0;                                                        \
      ua[3] = hi ? pk3 : sh1;                                                        \
      short8 af = *(short8*)&ua;                                                     \
      __builtin_amdgcn_s_setprio(1);                                                 \
      _Pragma("unroll")                                                              \
      for (int d = 0; d < 8; ++d) {                                                  \
        short8 vf = *(const short8*)(smem + 65536 + (VP) * 32768 + vaddr[c] + d * 2048); \
        o[d] = __builtin_amdgcn_mfma_f32_32x32x16_bf16(af, vf, o[d], 0, 0, 0);       \
      }                                                                              \
      __builtin_amdgcn_s_setprio(0);                                                 \
    }                                                                                \
  }

#define REGION(KC, KN, VP, VS, SCUR, SPRV, DOSTAGE)                                  \
  __syncthreads();                                                                   \
  if (DOSTAGE) { STAGE_K(KN); STAGE_V(VS); }                                         \
  kg += 32 * PD_; vg += 32;                                                          \
  QK_(SCUR, KC);                                                                     \
  SM_(SPRV);                                                                         \
  PV_(SPRV, VP);

  // ---- prologue: stage K(0)->kb0, V(0)->vb0; region 0 (no SM/PV) ----
  STAGE_K(0); STAGE_V(0);
  kg += 32 * PD_; vg += 32;
  __syncthreads();
  STAGE_K(1); STAGE_V(1);
  kg += 32 * PD_; vg += 32;
  QK_(sA, 0);

  // ---- main loop: t = 1..60 (10 x 6 regions, all indices literal) ----
#pragma unroll 1
  for (int it = 0; it < 10; ++it) {
    REGION(1, 0, 0, 2, sB, sA, 1)   // t%6==1
    REGION(0, 1, 1, 0, sA, sB, 1)   // t%6==2
    REGION(1, 0, 2, 1, sB, sA, 1)   // t%6==3
    REGION(0, 1, 0, 2, sA, sB, 1)   // t%6==4
    REGION(1, 0, 1, 0, sB, sA, 1)   // t%6==5
    REGION(0, 1, 2, 1, sA, sB, 1)   // t%6==0
  }
  // ---- tail: t = 61, 62, 63 (63 stages nothing) + epilogue SM/PV(63) ----
  REGION(1, 0, 0, 2, sB, sA, 1)
  REGION(0, 1, 1, 0, sA, sB, 1)
  REGION(1, 0, 2, 1, sB, sA, 0)
  SM_(sB);
  PV_(sB, 0);

  // ---- merge key-half pairs (w <-> w^4 share q-rows); reuse smem ----
  __syncthreads();
  float* sMm = (float*)smem;               // [8][32]
  float* sMl = (float*)(smem + 1024);      // [4][32]
  float* dep = (float*)(smem + 4096);      // 4 x 8320 floats
  if (!hi) sMm[w * 32 + l31] = mrun;
  __syncthreads();
  {
    float mo = sMm[(w ^ 4) * 32 + l31];
    float mf = fmaxf(mrun, mo);
    float sc = exp2f(mrun - mf);
    lrun *= sc;
#pragma unroll
    for (int r = 0; r < 16; ++r) {
      float rr = __shfl(sc, (r & 3) + 8 * (r >> 2) + 4 * hi, 64);
#pragma unroll
      for (int d = 0; d < 8; ++d) o[d][r] *= rr;
    }
    if (w >= 4 && !hi) sMl[(w - 4) * 32 + l31] = lrun;
  }
  __syncthreads();
  if (w >= 4) {                            // kh=1 deposits scaled o
    float* rg = dep + (size_t)qg * 8320;
#pragma unroll
    for (int d = 0; d < 8; ++d)
#pragma unroll
      for (int r4 = 0; r4 < 4; ++r4) {
        f32x4 v;
#pragma unroll
        for (int j = 0; j < 4; ++j) v[j] = o[d][4 * r4 + j];
        *(f32x4*)&rg[(size_t)(d * 4 + r4) * 260 + lane * 4] = v;
      }
  }
  __syncthreads();
  if (w < 4) {                             // kh=0 combines + epilogue
    float* rg = dep + (size_t)qg * 8320;
#pragma unroll
    for (int d = 0; d < 8; ++d)
#pragma unroll
      for (int r4 = 0; r4 < 4; ++r4) {
        f32x4 v = *(const f32x4*)&rg[(size_t)(d * 4 + r4) * 260 + lane * 4];
#pragma unroll
        for (int j = 0; j < 4; ++j) o[d][4 * r4 + j] += v[j];
      }
    lrun += sMl[qg * 32 + l31];
    float inv = 1.0f / lrun;
    const int bb = head >> 1, hh = head & 1;
#pragma unroll
    for (int r = 0; r < 16; ++r) {
      int q = qb * 128 + qg * 32 + (r & 3) + 8 * (r >> 2) + 4 * hi;
      float iv = __shfl(inv, (r & 3) + 8 * (r >> 2) + 4 * hi, 64);
      size_t base = ((size_t)(bb * S_ + q)) * D_ + hh * PD_;
#pragma unroll
      for (int d = 0; d < 8; ++d)
        ATT[base + d * 32 + l31] = f2bf(o[d][r] * iv);
    }
  }
#undef STAGE_K
#undef STAGE_V
#undef QK_
#undef SM_
#undef PV_
#undef REGION
}

// ---------------- launcher ----------------
extern "C" void kernel_launch(void* const* d_in, const int* in_sizes, int n_in,
                              void* d_out, int out_size, void* d_ws, size_t ws_size,
                              hipStream_t stream) {
  const float* x  = (const float*)d_in[0];
  const float* Wq = (const float*)d_in[1];
  const float* bq = (const float*)d_in[2];
  const float* Wk = (const float*)d_in[3];
  const float* bk = (const float*)d_in[4];
  const float* Wv = (const float*)d_in[5];
  const float* bv = (const float*)d_in[6];
  const float* Wo = (const float*)d_in[7];
  const float* bo = (const float*)d_in[8];
  float* out = (float*)d_out;

  char* ws = (char*)d_ws;
  const size_t WSZ = (size_t)D_ * D_ * 2;             // 512KB per transposed weight
  const size_t QSZ = (size_t)B_ * H_ * S_ * PD_ * 2;  // 16.78MB
  short* wtq = (short*)(ws);
  short* wtk = (short*)(ws + WSZ);
  short* wtv = (short*)(ws + 2 * WSZ);
  short* wto = (short*)(ws + 3 * WSZ);
  short* Qw  = (short*)(ws + 4 * WSZ);
  short* Kw  = (short*)(ws + 4 * WSZ + QSZ);
  short* Vw  = (short*)(ws + 4 * WSZ + 2 * QSZ);
  short* ATT = (short*)(ws + 4 * WSZ + 3 * QSZ);  // also used as xb (dead before attn writes)
  short* XB  = ATT;
  short* Vtp = (short*)d_out;  // V^T scratch lives in d_out; overwritten by final GEMM

  convert_x_kernel<<<dim3(2048), dim3(256), 0, stream>>>(x, XB, (B_ * S_ * D_) / 8);
  transpose_w<<<dim3(16, 16, 4), dim3(256), 0, stream>>>(Wq, Wk, Wv, Wo, wtq, wtk, wtv, wto);
  gemm_bt<0><<<dim3(128, 4, 3), dim3(256), 0, stream>>>(
      XB, wtq, wtk, wtv, bq, bk, bv, Qw, Kw, Vw, (float*)nullptr);
  transpose_v<<<dim3(64, 4, 8), dim3(256), 0, stream>>>(Vw, Vtp);
  attn6_kernel<<<dim3(256), dim3(512), 0, stream>>>(Qw, Kw, Vtp, ATT);
  gemm_bt<1><<<dim3(128, 4, 1), dim3(256), 0, stream>>>(
      ATT, wto, wto, wto, bo, bo, bo, nullptr, nullptr, nullptr, out);
}

// Round 8
// 419.833 us; speedup vs baseline: 2.8107x; 1.1635x over previous
//
#include <hip/hip_runtime.h>
#include <hip/hip_bf16.h>

// MultiHeadAttention: B=4, S=4096, D=512, H=2, PD=256, fp32 in/out.
// R8 = R7 (correctness-proven deferred-SM pipeline) with register-pressure
// shaves to eliminate the scratch spill: single-chain QK accumulator (-32 regs)
// and XOR-folded kbase/vbase LDS addressing (-5 regs). Target <=256 regs/wave.

#define B_  4
#define S_  4096
#define D_  512
#define H_  2
#define PD_ 256
#define QSCALE 0.09016844f   // (1/sqrt(256)) * log2(e)

typedef __attribute__((ext_vector_type(4))) float f32x4;
typedef __attribute__((ext_vector_type(16))) float f32x16;
typedef __attribute__((ext_vector_type(8))) short short8;
typedef __attribute__((ext_vector_type(4))) short short4v;
typedef __attribute__((ext_vector_type(4))) unsigned u32x4;

static __device__ __forceinline__ short f2bf(float f) {
  unsigned u = __float_as_uint(f);
  u += 0x7fffu + ((u >> 16) & 1u);
  return (short)(u >> 16);
}
static __device__ __forceinline__ unsigned cvtpk(float a, float b) {
  unsigned r;
  asm("v_cvt_pk_bf16_f32 %0, %1, %2" : "=v"(r) : "v"(a), "v"(b));
  return r;
}
static __device__ __forceinline__ void gload16(const short* g, const short* l) {
  __builtin_amdgcn_global_load_lds((const __attribute__((address_space(1))) void*)g,
                                   (__attribute__((address_space(3))) void*)l,
                                   16, 0, 0);
}

// ---------------- kernel: convert x (f32) -> bf16 ----------------
__global__ void convert_x_kernel(const float* __restrict__ x, short* __restrict__ xb, int n8) {
  int i = blockIdx.x * blockDim.x + threadIdx.x;
  int stride = gridDim.x * blockDim.x;
  for (; i < n8; i += stride) {
    const f32x4* p = (const f32x4*)(x + (size_t)i * 8);
    f32x4 a = p[0], b = p[1];
    short8 v;
    v[0] = f2bf(a[0]); v[1] = f2bf(a[1]); v[2] = f2bf(a[2]); v[3] = f2bf(a[3]);
    v[4] = f2bf(b[0]); v[5] = f2bf(b[1]); v[6] = f2bf(b[2]); v[7] = f2bf(b[3]);
    *(short8*)(xb + (size_t)i * 8) = v;
  }
}

// ---------------- kernel: transpose W[k][n] f32 -> Wt[n][k] bf16 ----------------
__global__ __launch_bounds__(256) void transpose_w(
    const float* __restrict__ W0, const float* __restrict__ W1,
    const float* __restrict__ W2, const float* __restrict__ W3,
    short* __restrict__ T0, short* __restrict__ T1,
    short* __restrict__ T2, short* __restrict__ T3) {
  const float* W = (blockIdx.z == 0) ? W0 : (blockIdx.z == 1) ? W1 : (blockIdx.z == 2) ? W2 : W3;
  short* T = (blockIdx.z == 0) ? T0 : (blockIdx.z == 1) ? T1 : (blockIdx.z == 2) ? T2 : T3;
  __shared__ float tile[32][33];
  int tx = threadIdx.x & 31, ty = threadIdx.x >> 5;
  int r0 = blockIdx.x * 32, c0 = blockIdx.y * 32;
#pragma unroll
  for (int i = 0; i < 4; ++i)
    tile[ty + 8 * i][tx] = W[(size_t)(r0 + ty + 8 * i) * D_ + c0 + tx];
  __syncthreads();
#pragma unroll
  for (int i = 0; i < 4; ++i)
    T[(size_t)(c0 + ty + 8 * i) * D_ + r0 + tx] = f2bf(tile[tx][ty + 8 * i]);
}

// ---------------- kernel: transpose V (bf16) -> Vt[h][d][s] ----------------
// chunk-XOR pre-swizzle within each 32-key granule: slot = ((s>>3)&3) ^ ((d>>3)&3)
__global__ __launch_bounds__(256) void transpose_v(
    const short* __restrict__ Vw, short* __restrict__ Vt) {
  __shared__ short tile[64][68];
  int h = blockIdx.z;
  int s0 = blockIdx.x * 64, d0 = blockIdx.y * 64;
  const short* src = Vw + (size_t)h * S_ * PD_;
  short* dst = Vt + (size_t)h * S_ * PD_;
  int tx = threadIdx.x & 15, ty = threadIdx.x >> 4;
#pragma unroll
  for (int i = 0; i < 4; ++i) {
    short4v v = *(const short4v*)(src + (size_t)(s0 + ty + 16 * i) * PD_ + d0 + tx * 4);
    *(short4v*)&tile[ty + 16 * i][tx * 4] = v;
  }
  __syncthreads();
#pragma unroll
  for (int i = 0; i < 4; ++i) {
    int d = d0 + ty + 16 * i;
    short4v v;
#pragma unroll
    for (int j = 0; j < 4; ++j) v[j] = tile[tx * 4 + j][ty + 16 * i];
    int swz = ((tx >> 1) & 3) ^ ((d >> 3) & 3);   // chunk slot within 32-granule
    *(short4v*)(dst + (size_t)d * S_ + s0 + (tx >> 3) * 32 + swz * 8 + (tx & 1) * 4) = v;
  }
}

// ---------------- GEMM: C[M,N] = A[M,512](bf16) * Bt[N,512](bf16)^T + bias ----------------
// MODE 0: z=0 Q (scaled by QSCALE), z=1 K (chunk-XOR pre-swizzled), z=2 V.
// MODE 1: single weight, dense f32 out + bias.
template <int MODE>
__global__ __launch_bounds__(256, 2) void gemm_bt(
    const short* __restrict__ A,
    const short* __restrict__ Bt0, const short* __restrict__ Bt1, const short* __restrict__ Bt2,
    const float* __restrict__ b0, const float* __restrict__ b1, const float* __restrict__ b2,
    short* __restrict__ o0, short* __restrict__ o1, short* __restrict__ o2,
    float* __restrict__ fout) {
  __shared__ short sA[128 * 72];
  __shared__ short sB[128 * 72];

  const int tid = threadIdx.x;
  const int lane = tid & 63, wid = tid >> 6;
  const int wr = wid >> 1, wc = wid & 1;
  const int l15 = lane & 15, g = lane >> 4;
  const int m0 = blockIdx.x * 128, n0 = blockIdx.y * 128;

  const short* Bt = (MODE == 0) ? ((blockIdx.z == 0) ? Bt0 : (blockIdx.z == 1) ? Bt1 : Bt2) : Bt0;
  const float* bias = (MODE == 0) ? ((blockIdx.z == 0) ? b0 : (blockIdx.z == 1) ? b1 : b2) : b0;

  short8 pa[4], pb[4];

  auto loadT = [&](int kt) {
#pragma unroll
    for (int i = 0; i < 4; ++i) {
      int slot = tid + 256 * i;
      int r = slot >> 3, gg = slot & 7;
      pa[i] = *(const short8*)(A + (size_t)(m0 + r) * D_ + kt * 64 + 8 * gg);
      pb[i] = *(const short8*)(Bt + (size_t)(n0 + r) * D_ + kt * 64 + 8 * gg);
    }
  };
  auto storeT = [&]() {
#pragma unroll
    for (int i = 0; i < 4; ++i) {
      int slot = tid + 256 * i;
      int r = slot >> 3, gg = slot & 7;
      *(short8*)&sA[r * 72 + 8 * gg] = pa[i];
      *(short8*)&sB[r * 72 + 8 * gg] = pb[i];
    }
  };

  f32x4 acc[4][4];
#pragma unroll
  for (int i = 0; i < 4; ++i)
#pragma unroll
    for (int j = 0; j < 4; ++j) acc[i][j] = (f32x4)0.0f;

  loadT(0);
#pragma unroll 1
  for (int kt = 0; kt < 8; ++kt) {
    __syncthreads();
    storeT();
    if (kt < 7) loadT(kt + 1);
    __syncthreads();
#pragma unroll
    for (int s = 0; s < 2; ++s) {
      short8 a[4], b[4];
#pragma unroll
      for (int fr = 0; fr < 4; ++fr)
        a[fr] = *(const short8*)&sA[(wr * 64 + fr * 16 + l15) * 72 + 32 * s + 8 * g];
#pragma unroll
      for (int fc = 0; fc < 4; ++fc)
        b[fc] = *(const short8*)&sB[(wc * 64 + fc * 16 + l15) * 72 + 32 * s + 8 * g];
#pragma unroll
      for (int fr = 0; fr < 4; ++fr)
#pragma unroll
        for (int fc = 0; fc < 4; ++fc)
          acc[fr][fc] = __builtin_amdgcn_mfma_f32_16x16x32_bf16(a[fr], b[fc], acc[fr][fc], 0, 0, 0);
    }
  }

  if (MODE == 0) {
    short* dst = (blockIdx.z == 0) ? o0 : (blockIdx.z == 1) ? o1 : o2;
    const bool kswz = (blockIdx.z == 1);
    const float sc = (blockIdx.z == 0) ? QSCALE : 1.0f;
#pragma unroll
    for (int fc = 0; fc < 4; ++fc) {
      int n = n0 + wc * 64 + fc * 16 + l15;
      float bvv = bias[n];
      int h = n >> 8, pd = n & 255;
#pragma unroll
      for (int fr = 0; fr < 4; ++fr)
#pragma unroll
        for (int r = 0; r < 4; ++r) {
          int m = m0 + wr * 64 + fr * 16 + 4 * g + r;
          int bb = m >> 12, ss = m & 4095;
          int pdw = pd;
          if (kswz) {
            int ch = pd >> 3;
            pdw = (pd & 7) | (((ch & 24) | ((ch & 7) ^ (ss & 7))) << 3);
          }
          dst[((size_t)((bb * H_ + h) * S_ + ss)) * PD_ + pdw] = f2bf((acc[fr][fc][r] + bvv) * sc);
        }
    }
  } else {
#pragma unroll
    for (int fc = 0; fc < 4; ++fc) {
      int n = n0 + wc * 64 + fc * 16 + l15;
      float bvv = bias[n];
#pragma unroll
      for (int fr = 0; fr < 4; ++fr)
#pragma unroll
        for (int r = 0; r < 4; ++r) {
          int m = m0 + wr * 64 + fr * 16 + 4 * g + r;
          fout[(size_t)m * D_ + n] = acc[fr][fc][r] + bvv;
        }
    }
  }
}

// ---------------- flash attention R8: deferred-SM pipeline, reg-trimmed ----------------
// 8 waves (512 thr): kh = w>>2 (key half), qg = w&3 (32-q group). 128 q/block.
// LDS 160KB exactly: K [2 buf][2 half][32 key][32 chunk*16B] at 0 (64KB),
//                    V [3 buf][2 half][256 d][4 chunk*16B] at 65536 (96KB).
// Region t: barrier; stage K(t+1)->kb[(t+1)&1], V(t+1)->vb[(t+1)%3];
//           QK(t) from kb[t&1]; SM(t-1); PV(t-1) from vb[(t-1)%3].
__global__ __launch_bounds__(512, 2) void attn8_kernel(
    const short* __restrict__ Qw, const short* __restrict__ Kw,
    const short* __restrict__ Vt, short* __restrict__ ATT) {
  __shared__ __align__(16) char smem[163840];

  const int tid = threadIdx.x, lane = tid & 63, w = tid >> 6;
  const int l31 = lane & 31, hi = lane >> 5;
  const int head = blockIdx.x & 7, qb = blockIdx.x >> 3;
  const int kh = w >> 2, qg = w & 3;
  const size_t hoff = (size_t)head * S_ * PD_;
  const short* Qh = Qw + hoff;
  const short* Vh = Vt + hoff;                 // [PD][S], pre-swizzled 32-granule

  // Q fragments (B-operand of swapped QK); QSCALE pre-folded.
  const int qrow = qb * 128 + qg * 32 + l31;
  short8 qf[16];
#pragma unroll
  for (int dc = 0; dc < 16; ++dc)
    qf[dc] = *(const short8*)(Qh + (size_t)qrow * PD_ + dc * 16 + hi * 8);

  // XOR-folded LDS read bases (bit-exact vs R7's kaddr[]/vaddr[]):
  // kaddr[b] = kbase ^ (b<<5); vaddr[c] = vbase ^ (c<<5)  (65536 folded into vbase)
  const int pp = (l31 >> 1) & 3, q3 = l31 >> 3;
  const int kbase = kh * 16384 + l31 * 512 + (pp << 5) + ((hi ^ (l31 & 1)) << 4);
  const int vbase = 65536 + kh * 16384 + l31 * 64 + ((hi ^ (q3 & 1)) << 4) + ((q3 >> 1) << 5);

  // staging bases
  const int lk0 = tid * 16;                        // LDS byte base (K and V)
  const int gk0 = (tid >> 5) * PD_ + (tid & 31) * 8;  // K global short-offset
  const int gv0 = (tid >> 2) * S_ + (tid & 3) * 8;    // V global short-offset
  const short* kg = Kw + hoff;
  const short* vg = Vh;

  f32x16 o[8];
#pragma unroll
  for (int i = 0; i < 8; ++i) o[i] = (f32x16)0.0f;
  f32x16 sA, sB;
  float mrun = -3.0e38f, lrun = 0.0f;

#define STAGE_K(KN)                                                                  \
  gload16(kg + gk0,          (const short*)(smem + (KN) * 32768 + lk0));             \
  gload16(kg + gk0 + 4096,   (const short*)(smem + (KN) * 32768 + 8192 + lk0));      \
  gload16(kg + gk0 + 524288, (const short*)(smem + (KN) * 32768 + 16384 + lk0));     \
  gload16(kg + gk0 + 528384, (const short*)(smem + (KN) * 32768 + 24576 + lk0));

#define STAGE_V(VS)                                                                  \
  gload16(vg + gv0,          (const short*)(smem + 65536 + (VS) * 32768 + lk0));     \
  gload16(vg + gv0 + 524288, (const short*)(smem + 65536 + (VS) * 32768 + 8192 + lk0)); \
  gload16(vg + gv0 + 2048,   (const short*)(smem + 65536 + (VS) * 32768 + 16384 + lk0)); \
  gload16(vg + gv0 + 526336, (const short*)(smem + 65536 + (VS) * 32768 + 24576 + lk0));

#define QK_(SCUR, KC)                                                                \
  {                                                                                  \
    SCUR = (f32x16)0.0f;                                                             \
    __builtin_amdgcn_s_setprio(1);                                                   \
    _Pragma("unroll")                                                                \
    for (int b = 0; b < 4; ++b) {                                                    \
      const int xb = kbase ^ (b << 5);                                               \
      _Pragma("unroll")                                                              \
      for (int a = 0; a < 4; ++a) {                                                  \
        short8 kf = *(const short8*)(smem + (KC) * 32768 + xb + a * 128);            \
        SCUR = __builtin_amdgcn_mfma_f32_32x32x16_bf16(kf, qf[4 * a + b], SCUR, 0, 0, 0); \
      }                                                                              \
    }                                                                                \
    __builtin_amdgcn_s_setprio(0);                                                   \
  }

#define SM_(S)                                                                       \
  {                                                                                  \
    float t0 = fmaxf(S[0], S[1]),   t1 = fmaxf(S[2], S[3]);                          \
    float t2 = fmaxf(S[4], S[5]),   t3 = fmaxf(S[6], S[7]);                          \
    float t4 = fmaxf(S[8], S[9]),   t5 = fmaxf(S[10], S[11]);                        \
    float t6 = fmaxf(S[12], S[13]), t7 = fmaxf(S[14], S[15]);                        \
    t0 = fmaxf(t0, t1); t2 = fmaxf(t2, t3); t4 = fmaxf(t4, t5); t6 = fmaxf(t6, t7);  \
    t0 = fmaxf(t0, t2); t4 = fmaxf(t4, t6);                                          \
    float tmax = fmaxf(t0, t4);                                                      \
    tmax = fmaxf(tmax, __shfl_xor(tmax, 32));                                        \
    if (!__all(tmax <= mrun + 8.0f)) {                                               \
      float mn = fmaxf(mrun, tmax);                                                  \
      float resc = exp2f(mrun - mn);                                                 \
      mrun = mn; lrun *= resc;                                                       \
      _Pragma("unroll")                                                              \
      for (int r = 0; r < 16; ++r) {                                                 \
        float rr = __shfl(resc, (r & 3) + 8 * (r >> 2) + 4 * hi, 64);                \
        _Pragma("unroll")                                                            \
        for (int d = 0; d < 8; ++d) o[d][r] *= rr;                                   \
      }                                                                              \
    }                                                                                \
    _Pragma("unroll")                                                                \
    for (int r = 0; r < 16; ++r) S[r] = exp2f(S[r] - mrun);                          \
    float u0 = (S[0] + S[1]) + (S[2] + S[3]);                                        \
    float u1 = (S[4] + S[5]) + (S[6] + S[7]);                                        \
    u0 += (S[8] + S[9]) + (S[10] + S[11]);                                           \
    u1 += (S[12] + S[13]) + (S[14] + S[15]);                                         \
    float ls = u0 + u1;                                                              \
    ls += __shfl_xor(ls, 32);                                                        \
    lrun += ls;                                                                      \
  }

#define PV_(S, VP)                                                                   \
  {                                                                                  \
    _Pragma("unroll")                                                                \
    for (int c = 0; c < 2; ++c) {                                                    \
      unsigned pk0 = cvtpk(S[8 * c + 0], S[8 * c + 1]);                              \
      unsigned pk1 = cvtpk(S[8 * c + 2], S[8 * c + 3]);                              \
      unsigned pk2 = cvtpk(S[8 * c + 4], S[8 * c + 5]);                              \
      unsigned pk3 = cvtpk(S[8 * c + 6], S[8 * c + 7]);                              \
      unsigned sh0 = __shfl_xor(pk0, 32);                                            \
      unsigned sh1 = __shfl_xor(pk1, 32);                                            \
      unsigned sh2 = __shfl_xor(pk2, 32);                                            \
      unsigned sh3 = __shfl_xor(pk3, 32);                                            \
      u32x4 ua;                                                                      \
      ua[0] = hi ? sh2 : pk0;                                                        \
      ua[1] = hi ? sh3 : pk1;                                                        \
      ua[2] = hi ? pk2 : sh0;                                                        \
      ua[3] = hi ? pk3 : sh1;                                                        \
      short8 af = *(short8*)&ua;                                                     \
      const int xv = (vbase ^ (c << 5)) + (VP) * 32768;                              \
      __builtin_amdgcn_s_setprio(1);                                                 \
      _Pragma("unroll")                                                              \
      for (int d = 0; d < 8; ++d) {                                                  \
        short8 vf = *(const short8*)(smem + xv + d * 2048);                          \
        o[d] = __builtin_amdgcn_mfma_f32_32x32x16_bf16(af, vf, o[d], 0, 0, 0);       \
      }                                                                              \
      __builtin_amdgcn_s_setprio(0);                                                 \
    }                                                                                \
  }

#define REGION(KC, KN, VP, VS, SCUR, SPRV, DOSTAGE)                                  \
  __syncthreads();                                                                   \
  if (DOSTAGE) { STAGE_K(KN); STAGE_V(VS); }                                         \
  kg += 32 * PD_; vg += 32;                                                          \
  QK_(SCUR, KC);                                                                     \
  SM_(SPRV);                                                                         \
  PV_(SPRV, VP);

  // ---- prologue: stage K(0)->kb0, V(0)->vb0; region 0 (no SM/PV) ----
  STAGE_K(0); STAGE_V(0);
  kg += 32 * PD_; vg += 32;
  __syncthreads();
  STAGE_K(1); STAGE_V(1);
  kg += 32 * PD_; vg += 32;
  QK_(sA, 0);

  // ---- main loop: t = 1..60 (10 x 6 regions, all indices literal) ----
#pragma unroll 1
  for (int it = 0; it < 10; ++it) {
    REGION(1, 0, 0, 2, sB, sA, 1)   // t%6==1
    REGION(0, 1, 1, 0, sA, sB, 1)   // t%6==2
    REGION(1, 0, 2, 1, sB, sA, 1)   // t%6==3
    REGION(0, 1, 0, 2, sA, sB, 1)   // t%6==4
    REGION(1, 0, 1, 0, sB, sA, 1)   // t%6==5
    REGION(0, 1, 2, 1, sA, sB, 1)   // t%6==0
  }
  // ---- tail: t = 61, 62, 63 (63 stages nothing) + epilogue SM/PV(63) ----
  REGION(1, 0, 0, 2, sB, sA, 1)
  REGION(0, 1, 1, 0, sA, sB, 1)
  REGION(1, 0, 2, 1, sB, sA, 0)
  SM_(sB);
  PV_(sB, 0);

  // ---- merge key-half pairs (w <-> w^4 share q-rows); reuse smem ----
  __syncthreads();
  float* sMm = (float*)smem;               // [8][32]
  float* sMl = (float*)(smem + 1024);      // [4][32]
  float* dep = (float*)(smem + 4096);      // 4 x 8320 floats
  if (!hi) sMm[w * 32 + l31] = mrun;
  __syncthreads();
  {
    float mo = sMm[(w ^ 4) * 32 + l31];
    float mf = fmaxf(mrun, mo);
    float sc = exp2f(mrun - mf);
    lrun *= sc;
#pragma unroll
    for (int r = 0; r < 16; ++r) {
      float rr = __shfl(sc, (r & 3) + 8 * (r >> 2) + 4 * hi, 64);
#pragma unroll
      for (int d = 0; d < 8; ++d) o[d][r] *= rr;
    }
    if (w >= 4 && !hi) sMl[(w - 4) * 32 + l31] = lrun;
  }
  __syncthreads();
  if (w >= 4) {                            // kh=1 deposits scaled o
    float* rg = dep + (size_t)qg * 8320;
#pragma unroll
    for (int d = 0; d < 8; ++d)
#pragma unroll
      for (int r4 = 0; r4 < 4; ++r4) {
        f32x4 v;
#pragma unroll
        for (int j = 0; j < 4; ++j) v[j] = o[d][4 * r4 + j];
        *(f32x4*)&rg[(size_t)(d * 4 + r4) * 260 + lane * 4] = v;
      }
  }
  __syncthreads();
  if (w < 4) {                             // kh=0 combines + epilogue
    float* rg = dep + (size_t)qg * 8320;
#pragma unroll
    for (int d = 0; d < 8; ++d)
#pragma unroll
      for (int r4 = 0; r4 < 4; ++r4) {
        f32x4 v = *(const f32x4*)&rg[(size_t)(d * 4 + r4) * 260 + lane * 4];
#pragma unroll
        for (int j = 0; j < 4; ++j) o[d][4 * r4 + j] += v[j];
      }
    lrun += sMl[qg * 32 + l31];
    float inv = 1.0f / lrun;
    const int bb = head >> 1, hh = head & 1;
#pragma unroll
    for (int r = 0; r < 16; ++r) {
      int q = qb * 128 + qg * 32 + (r & 3) + 8 * (r >> 2) + 4 * hi;
      float iv = __shfl(inv, (r & 3) + 8 * (r >> 2) + 4 * hi, 64);
      size_t base = ((size_t)(bb * S_ + q)) * D_ + hh * PD_;
#pragma unroll
      for (int d = 0; d < 8; ++d)
        ATT[base + d * 32 + l31] = f2bf(o[d][r] * iv);
    }
  }
#undef STAGE_K
#undef STAGE_V
#undef QK_
#undef SM_
#undef PV_
#undef REGION
}

// ---------------- launcher ----------------
extern "C" void kernel_launch(void* const* d_in, const int* in_sizes, int n_in,
                              void* d_out, int out_size, void* d_ws, size_t ws_size,
                              hipStream_t stream) {
  const float* x  = (const float*)d_in[0];
  const float* Wq = (const float*)d_in[1];
  const float* bq = (const float*)d_in[2];
  const float* Wk = (const float*)d_in[3];
  const float* bk = (const float*)d_in[4];
  const float* Wv = (const float*)d_in[5];
  const float* bv = (const float*)d_in[6];
  const float* Wo = (const float*)d_in[7];
  const float* bo = (const float*)d_in[8];
  float* out = (float*)d_out;

  char* ws = (char*)d_ws;
  const size_t WSZ = (size_t)D_ * D_ * 2;             // 512KB per transposed weight
  const size_t QSZ = (size_t)B_ * H_ * S_ * PD_ * 2;  // 16.78MB
  short* wtq = (short*)(ws);
  short* wtk = (short*)(ws + WSZ);
  short* wtv = (short*)(ws + 2 * WSZ);
  short* wto = (short*)(ws + 3 * WSZ);
  short* Qw  = (short*)(ws + 4 * WSZ);
  short* Kw  = (short*)(ws + 4 * WSZ + QSZ);
  short* Vw  = (short*)(ws + 4 * WSZ + 2 * QSZ);
  short* ATT = (short*)(ws + 4 * WSZ + 3 * QSZ);  // also used as xb (dead before attn writes)
  short* XB  = ATT;
  short* Vtp = (short*)d_out;  // V^T scratch lives in d_out; overwritten by final GEMM

  convert_x_kernel<<<dim3(2048), dim3(256), 0, stream>>>(x, XB, (B_ * S_ * D_) / 8);
  transpose_w<<<dim3(16, 16, 4), dim3(256), 0, stream>>>(Wq, Wk, Wv, Wo, wtq, wtk, wtv, wto);
  gemm_bt<0><<<dim3(128, 4, 3), dim3(256), 0, stream>>>(
      XB, wtq, wtk, wtv, bq, bk, bv, Qw, Kw, Vw, (float*)nullptr);
  transpose_v<<<dim3(64, 4, 8), dim3(256), 0, stream>>>(Vw, Vtp);
  attn8_kernel<<<dim3(256), dim3(512), 0, stream>>>(Qw, Kw, Vtp, ATT);
  gemm_bt<1><<<dim3(128, 4, 1), dim3(256), 0, stream>>>(
      ATT, wto, wto, wto, bo, bo, bo, nullptr, nullptr, nullptr, out);
}